// Round 7
// baseline (555.426 us; speedup 1.0000x reference)
//
#include <hip/hip_runtime.h>
#include <math.h>

#define BB 8
#define PP 100
#define QQ 10000
#define MASK25 0x1555555555555ULL
#define NB6B (((QQ + 127) / 128) * BB)   // 632 total k6b blocks across all chunks

__device__ __forceinline__ float frcp(float x) { return __builtin_amdgcn_rcpf(x); }
__device__ __forceinline__ float ftanh(float x) {
    float e2 = __expf(2.0f * x);
    return 1.0f - 2.0f * frcp(e2 + 1.0f);
}
__device__ __forceinline__ unsigned short f2bf(float f) {
    unsigned int u = __float_as_uint(f);
    u += 0x7FFF + ((u >> 16) & 1);
    return (unsigned short)(u >> 16);
}
__device__ __forceinline__ float bf2f(unsigned short s) {
    return __uint_as_float(((unsigned int)s) << 16);
}

// ---------------- K1: majority vote + count_d + 2-bit pack  (+fused bin_d) ----------------
// grid (157, 8) x 256. Per-batch LAST block computes bin_d for its batch.
__global__ void k1_ghat(const int* __restrict__ M, unsigned long long* __restrict__ Mpk,
                        unsigned char* __restrict__ ghat, unsigned char* __restrict__ cd,
                        unsigned char* __restrict__ bind, int* __restrict__ ctr1) {
    int b = blockIdx.y;
    int tid = threadIdx.x;
    int qi = tid & 63, wv = tid >> 6;
    int q = blockIdx.x * 64 + qi;
    __shared__ unsigned int red[4][64];
    if (q < QQ) {
        const int* Mb = M + b * PP * QQ + q;
        int p0 = wv * 25;
        unsigned long long mp = 0ULL;
        #pragma unroll 5
        for (int i = 0; i < 25; i++) {
            unsigned long long m = (unsigned int)Mb[(p0 + i) * QQ];
            mp |= m << (2 * i);
        }
        Mpk[(size_t)(b * 4 + wv) * QQ + q] = mp;
        unsigned int c4 = 0;
        #pragma unroll
        for (int k = 0; k < 4; k++) {
            unsigned long long x = mp ^ (MASK25 * (unsigned long long)k);
            unsigned long long nx = ~x;
            unsigned long long bits = nx & (nx >> 1) & MASK25;
            c4 += (unsigned int)__popcll(bits) << (8 * k);
        }
        red[wv][qi] = c4;
    } else red[wv][qi] = 0;
    __syncthreads();
    if (wv == 0 && q < QQ) {
        unsigned int s = red[0][qi] + red[1][qi] + red[2][qi] + red[3][qi];
        int c0 = s & 255, c1 = (s >> 8) & 255, c2 = (s >> 16) & 255, c3 = (s >> 24) & 255;
        int g = 0, best = c0;
        if (c1 > best) { g = 1; best = c1; }
        if (c2 > best) { g = 2; best = c2; }
        if (c3 > best) { g = 3; best = c3; }
        ghat[b * QQ + q] = (unsigned char)g;
        cd[b * QQ + q] = (unsigned char)best;
    }

    // ---- fused bin_d: per-batch last block ----
    __shared__ unsigned short h4[256][101];
    __shared__ int pfx4[101];
    __shared__ int lastf;
    __threadfence();
    if (tid == 0) lastf = (atomicAdd(&ctr1[b], 1) == (int)gridDim.x - 1) ? 1 : 0;
    __syncthreads();
    if (lastf) {
        __threadfence();
        for (int v = 0; v < 101; v++) h4[tid][v] = 0;
        const int CH = (QQ + 255) / 256;               // 40
        int s0 = tid * CH, s1 = min(s0 + CH, QQ);
        const unsigned char* c = cd + b * QQ;
        __syncthreads();
        for (int qq = s0; qq < s1; qq++) h4[tid][c[qq]]++;
        __syncthreads();
        for (int v = tid; v < 101; v += 256) {
            int run = 0;
            for (int tt = 0; tt < 256; tt++) { int x = h4[tt][v]; h4[tt][v] = (unsigned short)run; run += x; }
            pfx4[v] = run;
        }
        __syncthreads();
        if (tid == 0) { int run = 0; for (int v = 0; v < 101; v++) { int x = pfx4[v]; pfx4[v] = run; run += x; } }
        __syncthreads();
        unsigned char* bd = bind + b * QQ;
        for (int qq = s0; qq < s1; qq++) {
            int v = c[qq];
            int r = pfx4[v] + (int)h4[tid][v];
            h4[tid][v]++;
            bd[qq] = (unsigned char)(r / 2000);
        }
    }
}

// ---------------- K2: count_a + a_k counts + pa  (+fused bin_a/binmask) ----------------
__global__ void k2_counts(const unsigned long long* __restrict__ Mpk, const unsigned char* __restrict__ ghat,
                          const unsigned char* __restrict__ bind, int* __restrict__ count_a,
                          float* __restrict__ pa, const float* __restrict__ cW1,
                          unsigned long long* __restrict__ binmask, int* __restrict__ ctr2) {
    int blk = blockIdx.x;
    int b = blk / PP, p = blk - b * PP;
    int t = threadIdx.x;
    int chunk = p / 25, sh = 2 * (p % 25);
    const unsigned long long* Mc = Mpk + (size_t)(b * 4 + chunk) * QQ;
    const unsigned char* gh = ghat + b * QQ;
    const unsigned char* bd = bind + b * QQ;
    int cnt = 0, k0 = 0, k1 = 0, k2 = 0, k3 = 0, k4 = 0;
    for (int q = t; q < QQ; q += 256) {
        int m = (int)((Mc[q] >> sh) & 3ULL);
        int mc = (m == (int)gh[q]);
        int bb = bd[q];
        cnt += mc;
        k0 += mc & (bb == 0); k1 += mc & (bb == 1); k2 += mc & (bb == 2);
        k3 += mc & (bb == 3); k4 += mc & (bb == 4);
    }
    __shared__ int red[4][6];
    int w = t >> 6, l = t & 63;
    int v[6] = {cnt, k0, k1, k2, k3, k4};
    #pragma unroll
    for (int i = 0; i < 6; i++) {
        int x = v[i];
        #pragma unroll
        for (int off = 32; off > 0; off >>= 1) x += __shfl_down(x, off);
        if (l == 0) red[w][i] = x;
    }
    __syncthreads();
    if (t == 0) {
        int s[6];
        #pragma unroll
        for (int i = 0; i < 6; i++) s[i] = red[0][i] + red[1][i] + red[2][i] + red[3][i];
        count_a[b * PP + p] = s[0];
        float fa0 = (float)s[0] / 10000.0f;
        float fk[5];
        #pragma unroll
        for (int k = 0; k < 5; k++) fk[k] = (float)s[1 + k] / 2000.0f;
        float* par = pa + (b * PP + p) * 12;
        #pragma unroll
        for (int j = 0; j < 10; j++) {
            float sj = fa0 * cW1[j];
            #pragma unroll
            for (int k = 0; k < 5; k++) sj = fmaf(fk[k], cW1[(1 + k) * 10 + j], sj);
            par[j] = sj;
        }
        par[10] = 0.f; par[11] = 0.f;
    }

    // ---- fused bin_a + binmask: global last block ----
    __shared__ int lf2;
    __threadfence();
    if (t == 0) lf2 = (atomicAdd(ctr2, 1) == BB * PP - 1) ? 1 : 0;
    __syncthreads();
    if (lf2) {
        __threadfence();
        __shared__ int ca[PP];
        __shared__ unsigned char bn[PP];
        for (int bb2 = 0; bb2 < BB; bb2++) {
            if (t < PP) ca[t] = count_a[bb2 * PP + t];
            __syncthreads();
            if (t < PP) {
                int me = ca[t], r = 0;
                for (int pp = 0; pp < PP; pp++) {
                    int cc = ca[pp];
                    r += (cc < me) || (cc == me && pp < t);
                }
                bn[t] = (unsigned char)(r / 20);
            }
            __syncthreads();
            if (t == 0) {
                unsigned long long bm[4][5];
                #pragma unroll
                for (int c = 0; c < 4; c++)
                    #pragma unroll
                    for (int k = 0; k < 5; k++) bm[c][k] = 0ULL;
                for (int pp = 0; pp < PP; pp++) bm[pp / 25][bn[pp]] |= 1ULL << (2 * (pp % 25));
                for (int c = 0; c < 4; c++)
                    for (int k = 0; k < 5; k++) binmask[(bb2 * 4 + c) * 5 + k] = bm[c][k];
            }
            __syncthreads();
        }
    }
}

// ---------------- K6a: Y producer (cor-MLP) + loss_cor  (r4-proven structure) ----------------
__launch_bounds__(256)
__global__ void k6a_y(const unsigned long long* __restrict__ Mpk, const int* __restrict__ G_true,
    const unsigned char* __restrict__ ghat, const unsigned char* __restrict__ cd,
    const float* __restrict__ pa_g, const unsigned long long* __restrict__ binmask,
    const float* __restrict__ cW1, const float* __restrict__ cb1,
    const float* __restrict__ cW2, const float* __restrict__ cb2,
    const float* __restrict__ cW3, const float* __restrict__ cb3,
    const float* __restrict__ cW4, const float* __restrict__ cb4,
    unsigned short* __restrict__ Yout, int b0, double* __restrict__ acc)
{
    int bl = blockIdx.y;
    int b = b0 + bl;
    int tid = threadIdx.x;
    int qi = tid & 63, wv = tid >> 6;
    int q = blockIdx.x * 64 + qi;

    __shared__ float w3_s[10][12], w1d_s[6][12], cb1_s[12];
    __shared__ float pd_s[64][11];
    __shared__ unsigned long long bm_s[4][5];
    __shared__ float wred[4];

    for (int i = tid; i < 120; i += 256) { int r = i / 12, c = i % 12;
        w3_s[r][c] = (c < 10) ? cW3[r * 10 + c] : 0.f; }
    for (int i = tid; i < 72; i += 256) { int r = i / 12, c = i % 12;
        w1d_s[r][c] = (c < 10) ? cW1[60 + r * 10 + c] : 0.f; }
    if (tid >= 128 && tid < 140) { int j = tid - 128; cb1_s[j] = (j < 10) ? cb1[j] : 0.f; }
    if (tid >= 160 && tid < 180) { int j = tid - 160; bm_s[j / 5][j % 5] = binmask[(b * 4 + j / 5) * 5 + j % 5]; }
    __syncthreads();

    // wave 0 computes pd for the 64 q's
    if (wv == 0 && q < QQ) {
        int g = (int)ghat[b * QQ + q];
        unsigned long long rep = MASK25 * (unsigned long long)g;
        int dc[5] = {0, 0, 0, 0, 0};
        #pragma unroll
        for (int c = 0; c < 4; c++) {
            unsigned long long mm = Mpk[(size_t)(b * 4 + c) * QQ + q];
            unsigned long long nx = ~(mm ^ rep);
            unsigned long long bits = nx & (nx >> 1) & MASK25;
            #pragma unroll
            for (int k = 0; k < 5; k++) dc[k] += __popcll(bits & bm_s[c][k]);
        }
        float dlist = (float)cd[b * QQ + q] * 0.01f;
        float dkv[5];
        #pragma unroll
        for (int k = 0; k < 5; k++) dkv[k] = dc[k] * 0.05f;
        #pragma unroll
        for (int j = 0; j < 10; j++) {
            float s = cb1_s[j];
            s = fmaf(dlist, w1d_s[0][j], s);
            #pragma unroll
            for (int k = 0; k < 5; k++) s = fmaf(dkv[k], w1d_s[1 + k][j], s);
            pd_s[qi][j] = s;
        }
    }
    __syncthreads();

    float lc = 0.f;
    if (q < QQ) {
        float pd[10];
        #pragma unroll
        for (int j = 0; j < 10; j++) pd[j] = pd_s[qi][j];
        unsigned long long mrun = Mpk[(size_t)(b * 4 + wv) * QQ + q];
        int gt = G_true[b * QQ + q];
        int p0 = wv * 25;
        unsigned short* Yrow = Yout + (size_t)bl * PP * QQ + q;
        const float* paB = pa_g + (size_t)b * PP * 12;
        float b4v = cb4[0];

        #pragma unroll 1
        for (int iq = 0; iq < 6; iq++) {
            int pA = p0 + iq * 4;
            float ha[4][10], hb[4][10];
            // layer1 (pa: uniform global -> s_load)
            #pragma unroll
            for (int x = 0; x < 4; x++) {
                const float* par = paB + (pA + x) * 12;
                #pragma unroll
                for (int j = 0; j < 10; j++) ha[x][j] = fmaxf(par[j] + pd[j], 0.f);
            }
            // layer2 (w2: uniform global -> SGPR operands)
            #pragma unroll
            for (int x = 0; x < 4; x++)
                #pragma unroll
                for (int j = 0; j < 10; j++) hb[x][j] = cb2[j];
            #pragma unroll
            for (int j1 = 0; j1 < 10; j1++) {
                #pragma unroll
                for (int j2 = 0; j2 < 10; j2++) {
                    float w = cW2[j1 * 10 + j2];
                    hb[0][j2] = fmaf(ha[0][j1], w, hb[0][j2]);
                    hb[1][j2] = fmaf(ha[1][j1], w, hb[1][j2]);
                    hb[2][j2] = fmaf(ha[2][j1], w, hb[2][j2]);
                    hb[3][j2] = fmaf(ha[3][j1], w, hb[3][j2]);
                }
            }
            // relu + layer3 (w3: LDS float4 rows, 1 fetch / 40 FMA)
            #pragma unroll
            for (int x = 0; x < 4; x++)
                #pragma unroll
                for (int j = 0; j < 10; j++) { hb[x][j] = fmaxf(hb[x][j], 0.f); ha[x][j] = cb3[j]; }
            #pragma unroll
            for (int j1 = 0; j1 < 10; j1++) {
                float wrow[12];
                const float4* wr = (const float4*)w3_s[j1];
                ((float4*)wrow)[0] = wr[0]; ((float4*)wrow)[1] = wr[1]; ((float4*)wrow)[2] = wr[2];
                #pragma unroll
                for (int j2 = 0; j2 < 10; j2++) {
                    float w = wrow[j2];
                    ha[0][j2] = fmaf(hb[0][j1], w, ha[0][j2]);
                    ha[1][j2] = fmaf(hb[1][j1], w, ha[1][j2]);
                    ha[2][j2] = fmaf(hb[2][j1], w, ha[2][j2]);
                    ha[3][j2] = fmaf(hb[3][j1], w, ha[3][j2]);
                }
            }
            // layer4 + sigmoid + store + loss
            #pragma unroll
            for (int x = 0; x < 4; x++) {
                float xx = b4v;
                #pragma unroll
                for (int j = 0; j < 10; j++) xx = fmaf(fmaxf(ha[x][j], 0.f), cW4[j], xx);
                float Y = frcp(1.0f + __expf(-xx));
                Yrow[(size_t)(pA + x) * QQ] = f2bf(Y);
                int m = (int)(mrun & 3ULL); mrun >>= 2;
                float yc = fminf(fmaxf(Y, 1e-12f), 1.0f - 1e-12f);
                lc += __logf((m == gt) ? yc : 1.0f - yc);
            }
        }
        { // 25th worker
            int pA = p0 + 24;
            const float* par = paB + pA * 12;
            float h1[10], h2[10];
            #pragma unroll
            for (int j = 0; j < 10; j++) { h1[j] = fmaxf(par[j] + pd[j], 0.f); h2[j] = cb2[j]; }
            #pragma unroll
            for (int j1 = 0; j1 < 10; j1++) {
                float x = h1[j1];
                #pragma unroll
                for (int j2 = 0; j2 < 10; j2++) h2[j2] = fmaf(x, cW2[j1 * 10 + j2], h2[j2]);
            }
            float h3[10];
            #pragma unroll
            for (int j = 0; j < 10; j++) { h2[j] = fmaxf(h2[j], 0.f); h3[j] = cb3[j]; }
            #pragma unroll
            for (int j1 = 0; j1 < 10; j1++) {
                float x = h2[j1];
                #pragma unroll
                for (int j2 = 0; j2 < 10; j2++) h3[j2] = fmaf(x, w3_s[j1][j2], h3[j2]);
            }
            float xx = b4v;
            #pragma unroll
            for (int j = 0; j < 10; j++) xx = fmaf(fmaxf(h3[j], 0.f), cW4[j], xx);
            float Y = frcp(1.0f + __expf(-xx));
            Yrow[(size_t)pA * QQ] = f2bf(Y);
            int m = (int)(mrun & 3ULL);
            float yc = fminf(fmaxf(Y, 1e-12f), 1.0f - 1e-12f);
            lc += __logf((m == gt) ? yc : 1.0f - yc);
        }
    }

    float v1 = lc;
    #pragma unroll
    for (int off = 32; off > 0; off >>= 1) v1 += __shfl_down(v1, off);
    if ((tid & 63) == 0) wred[tid >> 6] = v1;
    __syncthreads();
    if (tid == 0) atomicAdd(&acc[0], (double)(wred[0] + wred[1] + wred[2] + wred[3]));
}

// ---------------- K6b: ref-MLP consumer + loss_ref (+fused finalize) ----------------
// grid (79, nb) x 256; t = tid&3 (class), qs = tid>>2 -> 2 consecutive q's of 128.
// Y tile + rW1 staged in LDS; inner loop is pure LDS + VALU.
__launch_bounds__(256)
__global__ void k6b_ref(const unsigned long long* __restrict__ Mpk, const int* __restrict__ G_true,
    const unsigned short* __restrict__ Yg, const float* __restrict__ rW1,
    const float* __restrict__ rb1,
    const float* __restrict__ rW2, const float* __restrict__ rb2,
    const float* __restrict__ rW3, const float* __restrict__ rb3,
    const float* __restrict__ rW4, const float* __restrict__ rb4,
    int b0, double* __restrict__ acc, int* __restrict__ ctr3, float* __restrict__ out)
{
    int bl = blockIdx.y;
    int b = b0 + bl;
    int tid = threadIdx.x;
    int q0base = blockIdx.x * 128;

    __shared__ unsigned int Y_s[PP][64];
    __shared__ float rw1_s[PP][16];
    __shared__ float rw2_s[15][16], rw3_s[15][16];
    __shared__ float rw4_s[16], rb1_s[16], rb2_s[16], rb3_s[16];
    __shared__ float wred[4];

    // stage Y tile (u32 = 2 bf16), coalesced
    const unsigned int* Yw = (const unsigned int*)(Yg + (size_t)bl * PP * QQ);
    for (int i = tid; i < PP * 64; i += 256) {
        int p = i >> 6, w = i & 63;
        int q = q0base + w * 2;
        Y_s[p][w] = (q < QQ) ? Yw[((size_t)p * QQ + q) >> 1] : 0u;
    }
    for (int i = tid; i < PP * 16; i += 256) { int r = i >> 4, c = i & 15; rw1_s[r][c] = (c < 15) ? rW1[r * 15 + c] : 0.f; }
    for (int i = tid; i < 240; i += 256) { int r = i >> 4, c = i & 15;
        rw2_s[r][c] = (c < 15) ? rW2[r * 15 + c] : 0.f;
        rw3_s[r][c] = (c < 15) ? rW3[r * 15 + c] : 0.f; }
    if (tid < 16) rw4_s[tid] = (tid < 15) ? rW4[tid] : 0.f;
    else if (tid < 32) { int j = tid - 16; rb1_s[j] = (j < 15) ? rb1[j] : 0.f; }
    else if (tid < 48) { int j = tid - 32; rb2_s[j] = (j < 15) ? rb2[j] : 0.f; }
    else if (tid < 64) { int j = tid - 48; rb3_s[j] = (j < 15) ? rb3[j] : 0.f; }
    float rb4v = rb4[0];
    __syncthreads();

    int t = tid & 3, qs = tid >> 2;                // qs 0..63
    int q0 = q0base + qs * 2;
    bool act = (q0 < QQ);
    int qc = act ? q0 : 0;
    int2 gtv = *(const int2*)(G_true + b * QQ + qc);
    int gt0 = gtv.x, gt1 = gtv.y;

    float a0[15], a1[15];
    #pragma unroll
    for (int j = 0; j < 15; j++) { a0[j] = rb1_s[j]; a1[j] = rb1_s[j]; }

    const unsigned long long* Mp0 = Mpk + (size_t)b * 4 * QQ + qc;

    #pragma unroll 1
    for (int c = 0; c < 4; c++) {
        ulonglong2 mv = *(const ulonglong2*)(Mp0 + (size_t)c * QQ);
        unsigned long long mm0 = mv.x, mm1 = mv.y;
        #pragma unroll 1
        for (int i = 0; i < 25; i++) {
            int p = c * 25 + i;
            unsigned int yw = Y_s[p][qs];
            float y0 = bf2f((unsigned short)(yw & 0xffffu));
            float y1 = bf2f((unsigned short)(yw >> 16));
            int m0 = (int)(mm0 & 3ULL); mm0 >>= 2;
            int m1 = (int)(mm1 & 3ULL); mm1 >>= 2;
            float u0 = (m0 == t) ? y0 : (1.0f - y0) * (1.0f / 3.0f);
            float u1 = (m1 == t) ? y1 : (1.0f - y1) * (1.0f / 3.0f);
            float wrow[16];
            const float4* wr = (const float4*)rw1_s[p];
            ((float4*)wrow)[0] = wr[0]; ((float4*)wrow)[1] = wr[1];
            ((float4*)wrow)[2] = wr[2]; ((float4*)wrow)[3] = wr[3];
            #pragma unroll
            for (int j = 0; j < 15; j++) {
                a0[j] = fmaf(u0, wrow[j], a0[j]);
                a1[j] = fmaf(u1, wrow[j], a1[j]);
            }
        }
    }

    // tail for both q's, sharing weight-row fetches
    float g1a[15], g1b[15], g2a[15], g2b[15];
    #pragma unroll
    for (int j = 0; j < 15; j++) {
        g1a[j] = ftanh(a0[j]); g1b[j] = ftanh(a1[j]);
        g2a[j] = rb2_s[j];     g2b[j] = rb2_s[j];
    }
    #pragma unroll
    for (int j1 = 0; j1 < 15; j1++) {
        float wrow[16];
        const float4* wr = (const float4*)rw2_s[j1];
        ((float4*)wrow)[0] = wr[0]; ((float4*)wrow)[1] = wr[1];
        ((float4*)wrow)[2] = wr[2]; ((float4*)wrow)[3] = wr[3];
        float xa = g1a[j1], xb = g1b[j1];
        #pragma unroll
        for (int j2 = 0; j2 < 15; j2++) {
            g2a[j2] = fmaf(xa, wrow[j2], g2a[j2]);
            g2b[j2] = fmaf(xb, wrow[j2], g2b[j2]);
        }
    }
    #pragma unroll
    for (int j = 0; j < 15; j++) {
        g2a[j] = ftanh(g2a[j]); g2b[j] = ftanh(g2b[j]);
        a0[j] = rb3_s[j];       a1[j] = rb3_s[j];
    }
    #pragma unroll
    for (int j1 = 0; j1 < 15; j1++) {
        float wrow[16];
        const float4* wr = (const float4*)rw3_s[j1];
        ((float4*)wrow)[0] = wr[0]; ((float4*)wrow)[1] = wr[1];
        ((float4*)wrow)[2] = wr[2]; ((float4*)wrow)[3] = wr[3];
        float xa = g2a[j1], xb = g2b[j1];
        #pragma unroll
        for (int j2 = 0; j2 < 15; j2++) {
            a0[j2] = fmaf(xa, wrow[j2], a0[j2]);
            a1[j2] = fmaf(xb, wrow[j2], a1[j2]);
        }
    }
    float z0 = rb4v, z1 = rb4v;
    #pragma unroll
    for (int j = 0; j < 15; j++) {
        z0 = fmaf(ftanh(a0[j]), rw4_s[j], z0);
        z1 = fmaf(ftanh(a1[j]), rw4_s[j], z1);
    }

    float lrv = 0.f;
    {
        float zm = fmaxf(z0, __shfl_xor(z0, 1)); zm = fmaxf(zm, __shfl_xor(zm, 2));
        float ez = __expf(z0 - zm);
        float es = ez + __shfl_xor(ez, 1); es += __shfl_xor(es, 2);
        float prob = ez * frcp(es);
        float pm = fmaxf(prob, __shfl_xor(prob, 1)); pm = fmaxf(pm, __shfl_xor(pm, 2));
        float ep = __expf(prob - pm);
        float eps_ = ep + __shfl_xor(ep, 1); eps_ += __shfl_xor(eps_, 2);
        float lp = prob - (pm + __logf(eps_));
        float sel = (t == gt0) ? lp : 0.f;
        sel += __shfl_xor(sel, 1); sel += __shfl_xor(sel, 2);
        if (t == 0 && act) lrv += sel;
    }
    {
        float zm = fmaxf(z1, __shfl_xor(z1, 1)); zm = fmaxf(zm, __shfl_xor(zm, 2));
        float ez = __expf(z1 - zm);
        float es = ez + __shfl_xor(ez, 1); es += __shfl_xor(es, 2);
        float prob = ez * frcp(es);
        float pm = fmaxf(prob, __shfl_xor(prob, 1)); pm = fmaxf(pm, __shfl_xor(pm, 2));
        float ep = __expf(prob - pm);
        float eps_ = ep + __shfl_xor(ep, 1); eps_ += __shfl_xor(eps_, 2);
        float lp = prob - (pm + __logf(eps_));
        float sel = (t == gt1) ? lp : 0.f;
        sel += __shfl_xor(sel, 1); sel += __shfl_xor(sel, 2);
        if (t == 0 && act) lrv += sel;
    }

    float v = lrv;
    #pragma unroll
    for (int off = 32; off > 0; off >>= 1) v += __shfl_down(v, off);
    if ((tid & 63) == 0) wred[tid >> 6] = v;
    __syncthreads();
    if (tid == 0) {
        atomicAdd(&acc[1], (double)(wred[0] + wred[1] + wred[2] + wred[3]));
        __threadfence();
        if (atomicAdd(ctr3, 1) == NB6B - 1) {
            __threadfence();
            out[0] = (float)(-acc[0] / (double)(BB * PP * QQ));
            out[1] = (float)(-acc[1] / (double)(BB * QQ));
        }
    }
}

extern "C" void kernel_launch(void* const* d_in, const int* in_sizes, int n_in,
                              void* d_out, int out_size, void* d_ws, size_t ws_size,
                              hipStream_t stream) {
    const int*   M      = (const int*)d_in[0];
    const int*   G_true = (const int*)d_in[1];
    const float* cW1 = (const float*)d_in[2];  const float* cb1 = (const float*)d_in[3];
    const float* cW2 = (const float*)d_in[4];  const float* cb2 = (const float*)d_in[5];
    const float* cW3 = (const float*)d_in[6];  const float* cb3 = (const float*)d_in[7];
    const float* cW4 = (const float*)d_in[8];  const float* cb4 = (const float*)d_in[9];
    const float* rW1 = (const float*)d_in[10]; const float* rb1 = (const float*)d_in[11];
    const float* rW2 = (const float*)d_in[12]; const float* rb2 = (const float*)d_in[13];
    const float* rW3 = (const float*)d_in[14]; const float* rb3 = (const float*)d_in[15];
    const float* rW4 = (const float*)d_in[16]; const float* rb4 = (const float*)d_in[17];

    char* ws = (char*)d_ws;
    double* acc             = (double*)ws;                        // 16 B
    int* ctr1               = (int*)(ws + 16);                    // 8 ints
    int* ctr2               = (int*)(ws + 48);
    int* ctr3               = (int*)(ws + 52);
    float* pa               = (float*)(ws + 64);                  // 38400
    int* count_a            = (int*)(ws + 38464);                 // 3200
    unsigned char* ghat     = (unsigned char*)(ws + 41664);       // 80000
    unsigned char* cd       = (unsigned char*)(ws + 121664);      // 80000
    unsigned char* bind     = (unsigned char*)(ws + 201664);      // 80000
    unsigned long long* bmk = (unsigned long long*)(ws + 281664); // 1280
    unsigned long long* Mpk = (unsigned long long*)(ws + 282944); // 2,560,000
    unsigned short* Y       = (unsigned short*)(ws + 2842944);    // nb * 2,000,000

    const size_t FIXED_END = 2842944;
    const size_t PER_B_Y = (size_t)PP * QQ * 2;
    size_t avail = (ws_size > FIXED_END) ? ws_size - FIXED_END : 0;
    int nb = (int)(avail / PER_B_Y);
    if (nb < 1) nb = 1;
    if (nb > BB) nb = BB;

    hipMemsetAsync(d_ws, 0, 64, stream);           // zero acc + counters

    dim3 gq(157, BB);
    k1_ghat<<<gq, 256, 0, stream>>>(M, Mpk, ghat, cd, bind, ctr1);
    k2_counts<<<BB * PP, 256, 0, stream>>>(Mpk, ghat, bind, count_a, pa, cW1, bmk, ctr2);

    for (int b0 = 0; b0 < BB; b0 += nb) {
        int g = (BB - b0 < nb) ? (BB - b0) : nb;
        dim3 ga(157, g);
        dim3 gb(79, g);
        k6a_y<<<ga, 256, 0, stream>>>(Mpk, G_true, ghat, cd, pa, bmk,
            cW1, cb1, cW2, cb2, cW3, cb3, cW4, cb4, Y, b0, acc);
        k6b_ref<<<gb, 256, 0, stream>>>(Mpk, G_true, Y, rW1,
            rb1, rW2, rb2, rW3, rb3, rW4, rb4, b0, acc, ctr3, (float*)d_out);
    }
}

// Round 8
// 296.217 us; speedup vs baseline: 1.8751x; 1.8751x over previous
//
#include <hip/hip_runtime.h>
#include <math.h>

#define BB 8
#define PP 100
#define QQ 10000
#define MASK25 0x1555555555555ULL

__device__ __forceinline__ float frcp(float x) { return __builtin_amdgcn_rcpf(x); }
__device__ __forceinline__ float ftanh(float x) {
    float e2 = __expf(2.0f * x);
    return 1.0f - 2.0f * frcp(e2 + 1.0f);
}
__device__ __forceinline__ unsigned short f2bf(float f) {
    unsigned int u = __float_as_uint(f);
    u += 0x7FFF + ((u >> 16) & 1);
    return (unsigned short)(u >> 16);
}
__device__ __forceinline__ float bf2f(unsigned short s) {
    return __uint_as_float(((unsigned int)s) << 16);
}

// ---------------- K1: majority vote + count_d + 2-bit pack ----------------
__global__ void k1_ghat(const int* __restrict__ M, unsigned long long* __restrict__ Mpk,
                        unsigned char* __restrict__ ghat, unsigned char* __restrict__ cd) {
    int b = blockIdx.y;
    int tid = threadIdx.x;
    int qi = tid & 63, wv = tid >> 6;
    int q = blockIdx.x * 64 + qi;
    __shared__ unsigned int red[4][64];
    if (q < QQ) {
        const int* Mb = M + b * PP * QQ + q;
        int p0 = wv * 25;
        unsigned long long mp = 0ULL;
        #pragma unroll 5
        for (int i = 0; i < 25; i++) {
            unsigned long long m = (unsigned int)Mb[(p0 + i) * QQ];
            mp |= m << (2 * i);
        }
        Mpk[(size_t)(b * 4 + wv) * QQ + q] = mp;
        unsigned int c4 = 0;
        #pragma unroll
        for (int k = 0; k < 4; k++) {
            unsigned long long x = mp ^ (MASK25 * (unsigned long long)k);
            unsigned long long nx = ~x;
            unsigned long long bits = nx & (nx >> 1) & MASK25;
            c4 += (unsigned int)__popcll(bits) << (8 * k);
        }
        red[wv][qi] = c4;
    } else red[wv][qi] = 0;
    __syncthreads();
    if (wv == 0 && q < QQ) {
        unsigned int s = red[0][qi] + red[1][qi] + red[2][qi] + red[3][qi];
        int c0 = s & 255, c1 = (s >> 8) & 255, c2 = (s >> 16) & 255, c3 = (s >> 24) & 255;
        int g = 0, best = c0;
        if (c1 > best) { g = 1; best = c1; }
        if (c2 > best) { g = 2; best = c2; }
        if (c3 > best) { g = 3; best = c3; }
        ghat[b * QQ + q] = (unsigned char)g;
        cd[b * QQ + q] = (unsigned char)best;
    }
}

// ---------------- K4: bin_d = stable-argsort quantile bins of count_d ----------------
__global__ void k4_bind(const unsigned char* __restrict__ cd, unsigned char* __restrict__ bind) {
    int b = blockIdx.x, t = threadIdx.x;           // 256 threads
    __shared__ unsigned short h[256][101];
    __shared__ int pfx[101];
    for (int v = 0; v < 101; v++) h[t][v] = 0;
    const int CH = (QQ + 255) / 256;               // 40
    int q0 = t * CH, q1 = min(q0 + CH, QQ);
    const unsigned char* c = cd + b * QQ;
    __syncthreads();
    for (int q = q0; q < q1; q++) h[t][c[q]]++;
    __syncthreads();
    for (int v = t; v < 101; v += 256) {
        int run = 0;
        for (int tt = 0; tt < 256; tt++) { int x = h[tt][v]; h[tt][v] = (unsigned short)run; run += x; }
        pfx[v] = run;
    }
    __syncthreads();
    if (t == 0) { int run = 0; for (int v = 0; v < 101; v++) { int x = pfx[v]; pfx[v] = run; run += x; } }
    __syncthreads();
    unsigned char* bd = bind + b * QQ;
    for (int q = q0; q < q1; q++) {
        int v = c[q];
        int r = pfx[v] + (int)h[t][v];
        h[t][v]++;
        bd[q] = (unsigned char)(r / 2000);
    }
}

// ---------------- K2: count_a + a_k counts + first-layer worker partial pa ----------------
__global__ void k2_counts(const unsigned long long* __restrict__ Mpk, const unsigned char* __restrict__ ghat,
                          const unsigned char* __restrict__ bind, int* __restrict__ count_a,
                          float* __restrict__ pa, const float* __restrict__ cW1) {
    int blk = blockIdx.x;
    int b = blk / PP, p = blk - b * PP;
    int t = threadIdx.x;
    int chunk = p / 25, sh = 2 * (p % 25);
    const unsigned long long* Mc = Mpk + (size_t)(b * 4 + chunk) * QQ;
    const unsigned char* gh = ghat + b * QQ;
    const unsigned char* bd = bind + b * QQ;
    int cnt = 0, k0 = 0, k1 = 0, k2 = 0, k3 = 0, k4 = 0;
    for (int q = t; q < QQ; q += 256) {
        int m = (int)((Mc[q] >> sh) & 3ULL);
        int mc = (m == (int)gh[q]);
        int bb = bd[q];
        cnt += mc;
        k0 += mc & (bb == 0); k1 += mc & (bb == 1); k2 += mc & (bb == 2);
        k3 += mc & (bb == 3); k4 += mc & (bb == 4);
    }
    __shared__ int red[4][6];
    int w = t >> 6, l = t & 63;
    int v[6] = {cnt, k0, k1, k2, k3, k4};
    #pragma unroll
    for (int i = 0; i < 6; i++) {
        int x = v[i];
        #pragma unroll
        for (int off = 32; off > 0; off >>= 1) x += __shfl_down(x, off);
        if (l == 0) red[w][i] = x;
    }
    __syncthreads();
    if (t == 0) {
        int s[6];
        #pragma unroll
        for (int i = 0; i < 6; i++) s[i] = red[0][i] + red[1][i] + red[2][i] + red[3][i];
        count_a[b * PP + p] = s[0];
        float fa0 = (float)s[0] / 10000.0f;
        float fk[5];
        #pragma unroll
        for (int k = 0; k < 5; k++) fk[k] = (float)s[1 + k] / 2000.0f;
        float* par = pa + (b * PP + p) * 12;
        #pragma unroll
        for (int j = 0; j < 10; j++) {
            float sj = fa0 * cW1[j];
            #pragma unroll
            for (int k = 0; k < 5; k++) sj = fmaf(fk[k], cW1[(1 + k) * 10 + j], sj);
            par[j] = sj;
        }
        par[10] = 0.f; par[11] = 0.f;
    }
}

// ---------------- K3: bin_a stable rank + per-bin bitmasks ----------------
__global__ void k3_bina(const int* __restrict__ count_a, unsigned long long* __restrict__ binmask) {
    int b = blockIdx.x, p = threadIdx.x;           // 128 threads
    __shared__ int ca[PP];
    __shared__ unsigned char bn[PP];
    if (p < PP) ca[p] = count_a[b * PP + p];
    __syncthreads();
    if (p < PP) {
        int me = ca[p], r = 0;
        for (int pp = 0; pp < PP; pp++) {
            int cc = ca[pp];
            r += (cc < me) || (cc == me && pp < p);
        }
        bn[p] = (unsigned char)(r / 20);
    }
    __syncthreads();
    if (p == 0) {
        unsigned long long bm[4][5];
        #pragma unroll
        for (int c = 0; c < 4; c++)
            #pragma unroll
            for (int k = 0; k < 5; k++) bm[c][k] = 0ULL;
        for (int pp = 0; pp < PP; pp++) bm[pp / 25][bn[pp]] |= 1ULL << (2 * (pp % 25));
        for (int c = 0; c < 4; c++)
            for (int k = 0; k < 5; k++) binmask[(b * 4 + c) * 5 + k] = bm[c][k];
    }
}

// ---------------- K6a: Y producer (cor-MLP) + loss_cor  (r4-proven, DO NOT TOUCH) ----------------
__launch_bounds__(256)
__global__ void k6a_y(const unsigned long long* __restrict__ Mpk, const int* __restrict__ G_true,
    const unsigned char* __restrict__ ghat, const unsigned char* __restrict__ cd,
    const float* __restrict__ pa_g, const unsigned long long* __restrict__ binmask,
    const float* __restrict__ cW1, const float* __restrict__ cb1,
    const float* __restrict__ cW2, const float* __restrict__ cb2,
    const float* __restrict__ cW3, const float* __restrict__ cb3,
    const float* __restrict__ cW4, const float* __restrict__ cb4,
    unsigned short* __restrict__ Yout, int b0, double* __restrict__ acc)
{
    int bl = blockIdx.y;
    int b = b0 + bl;
    int tid = threadIdx.x;
    int qi = tid & 63, wv = tid >> 6;
    int q = blockIdx.x * 64 + qi;

    __shared__ float w3_s[10][12], w1d_s[6][12], cb1_s[12];
    __shared__ float pd_s[64][11];
    __shared__ unsigned long long bm_s[4][5];
    __shared__ float wred[4];

    for (int i = tid; i < 120; i += 256) { int r = i / 12, c = i % 12;
        w3_s[r][c] = (c < 10) ? cW3[r * 10 + c] : 0.f; }
    for (int i = tid; i < 72; i += 256) { int r = i / 12, c = i % 12;
        w1d_s[r][c] = (c < 10) ? cW1[60 + r * 10 + c] : 0.f; }
    if (tid >= 128 && tid < 140) { int j = tid - 128; cb1_s[j] = (j < 10) ? cb1[j] : 0.f; }
    if (tid >= 160 && tid < 180) { int j = tid - 160; bm_s[j / 5][j % 5] = binmask[(b * 4 + j / 5) * 5 + j % 5]; }
    __syncthreads();

    // wave 0 computes pd for the 64 q's
    if (wv == 0 && q < QQ) {
        int g = (int)ghat[b * QQ + q];
        unsigned long long rep = MASK25 * (unsigned long long)g;
        int dc[5] = {0, 0, 0, 0, 0};
        #pragma unroll
        for (int c = 0; c < 4; c++) {
            unsigned long long mm = Mpk[(size_t)(b * 4 + c) * QQ + q];
            unsigned long long nx = ~(mm ^ rep);
            unsigned long long bits = nx & (nx >> 1) & MASK25;
            #pragma unroll
            for (int k = 0; k < 5; k++) dc[k] += __popcll(bits & bm_s[c][k]);
        }
        float dlist = (float)cd[b * QQ + q] * 0.01f;
        float dkv[5];
        #pragma unroll
        for (int k = 0; k < 5; k++) dkv[k] = dc[k] * 0.05f;
        #pragma unroll
        for (int j = 0; j < 10; j++) {
            float s = cb1_s[j];
            s = fmaf(dlist, w1d_s[0][j], s);
            #pragma unroll
            for (int k = 0; k < 5; k++) s = fmaf(dkv[k], w1d_s[1 + k][j], s);
            pd_s[qi][j] = s;
        }
    }
    __syncthreads();

    float lc = 0.f;
    if (q < QQ) {
        float pd[10];
        #pragma unroll
        for (int j = 0; j < 10; j++) pd[j] = pd_s[qi][j];
        unsigned long long mrun = Mpk[(size_t)(b * 4 + wv) * QQ + q];
        int gt = G_true[b * QQ + q];
        int p0 = wv * 25;
        unsigned short* Yrow = Yout + (size_t)bl * PP * QQ + q;
        const float* paB = pa_g + (size_t)b * PP * 12;
        float b4v = cb4[0];

        #pragma unroll 1
        for (int iq = 0; iq < 6; iq++) {
            int pA = p0 + iq * 4;
            float ha[4][10], hb[4][10];
            // layer1 (pa: uniform global -> s_load)
            #pragma unroll
            for (int x = 0; x < 4; x++) {
                const float* par = paB + (pA + x) * 12;
                #pragma unroll
                for (int j = 0; j < 10; j++) ha[x][j] = fmaxf(par[j] + pd[j], 0.f);
            }
            // layer2 (w2: uniform global -> SGPR operands)
            #pragma unroll
            for (int x = 0; x < 4; x++)
                #pragma unroll
                for (int j = 0; j < 10; j++) hb[x][j] = cb2[j];
            #pragma unroll
            for (int j1 = 0; j1 < 10; j1++) {
                #pragma unroll
                for (int j2 = 0; j2 < 10; j2++) {
                    float w = cW2[j1 * 10 + j2];
                    hb[0][j2] = fmaf(ha[0][j1], w, hb[0][j2]);
                    hb[1][j2] = fmaf(ha[1][j1], w, hb[1][j2]);
                    hb[2][j2] = fmaf(ha[2][j1], w, hb[2][j2]);
                    hb[3][j2] = fmaf(ha[3][j1], w, hb[3][j2]);
                }
            }
            // relu + layer3 (w3: LDS float4 rows, 1 fetch / 40 FMA)
            #pragma unroll
            for (int x = 0; x < 4; x++)
                #pragma unroll
                for (int j = 0; j < 10; j++) { hb[x][j] = fmaxf(hb[x][j], 0.f); ha[x][j] = cb3[j]; }
            #pragma unroll
            for (int j1 = 0; j1 < 10; j1++) {
                float wrow[12];
                const float4* wr = (const float4*)w3_s[j1];
                ((float4*)wrow)[0] = wr[0]; ((float4*)wrow)[1] = wr[1]; ((float4*)wrow)[2] = wr[2];
                #pragma unroll
                for (int j2 = 0; j2 < 10; j2++) {
                    float w = wrow[j2];
                    ha[0][j2] = fmaf(hb[0][j1], w, ha[0][j2]);
                    ha[1][j2] = fmaf(hb[1][j1], w, ha[1][j2]);
                    ha[2][j2] = fmaf(hb[2][j1], w, ha[2][j2]);
                    ha[3][j2] = fmaf(hb[3][j1], w, ha[3][j2]);
                }
            }
            // layer4 + sigmoid + logsigmoid loss + store
            #pragma unroll
            for (int x = 0; x < 4; x++) {
                float xx = b4v;
                #pragma unroll
                for (int j = 0; j < 10; j++) xx = fmaf(fmaxf(ha[x][j], 0.f), cW4[j], xx);
                float e = __expf(-xx);
                float Y = frcp(1.0f + e);
                float L = __logf(1.0f + e);          // -log(sigmoid(xx))
                Yrow[(size_t)(pA + x) * QQ] = f2bf(Y);
                int m = (int)(mrun & 3ULL); mrun >>= 2;
                lc -= L + ((m == gt) ? 0.f : xx);
            }
        }
        { // 25th worker
            int pA = p0 + 24;
            const float* par = paB + pA * 12;
            float h1[10], h2[10];
            #pragma unroll
            for (int j = 0; j < 10; j++) { h1[j] = fmaxf(par[j] + pd[j], 0.f); h2[j] = cb2[j]; }
            #pragma unroll
            for (int j1 = 0; j1 < 10; j1++) {
                float x = h1[j1];
                #pragma unroll
                for (int j2 = 0; j2 < 10; j2++) h2[j2] = fmaf(x, cW2[j1 * 10 + j2], h2[j2]);
            }
            float h3[10];
            #pragma unroll
            for (int j = 0; j < 10; j++) { h2[j] = fmaxf(h2[j], 0.f); h3[j] = cb3[j]; }
            #pragma unroll
            for (int j1 = 0; j1 < 10; j1++) {
                float x = h2[j1];
                #pragma unroll
                for (int j2 = 0; j2 < 10; j2++) h3[j2] = fmaf(x, w3_s[j1][j2], h3[j2]);
            }
            float xx = b4v;
            #pragma unroll
            for (int j = 0; j < 10; j++) xx = fmaf(fmaxf(h3[j], 0.f), cW4[j], xx);
            float e = __expf(-xx);
            float Y = frcp(1.0f + e);
            float L = __logf(1.0f + e);
            Yrow[(size_t)pA * QQ] = f2bf(Y);
            int m = (int)(mrun & 3ULL);
            lc -= L + ((m == gt) ? 0.f : xx);
        }
    }

    float v1 = lc;
    #pragma unroll
    for (int off = 32; off > 0; off >>= 1) v1 += __shfl_down(v1, off);
    if ((tid & 63) == 0) wred[tid >> 6] = v1;
    __syncthreads();
    if (tid == 0) atomicAdd(&acc[0], (double)(wred[0] + wred[1] + wred[2] + wred[3]));
}

// ---------------- K6b: ref-MLP consumer + loss_ref (LDS-staged Y, no fusion) ----------------
// grid (79, nb) x 256; t = tid&3 (class), qs = tid>>2 -> 2 consecutive q's of 128.
__launch_bounds__(256)
__global__ void k6b_ref(const unsigned long long* __restrict__ Mpk, const int* __restrict__ G_true,
    const unsigned short* __restrict__ Yg, const float* __restrict__ rW1,
    const float* __restrict__ rb1,
    const float* __restrict__ rW2, const float* __restrict__ rb2,
    const float* __restrict__ rW3, const float* __restrict__ rb3,
    const float* __restrict__ rW4, const float* __restrict__ rb4,
    int b0, double* __restrict__ acc)
{
    int bl = blockIdx.y;
    int b = b0 + bl;
    int tid = threadIdx.x;
    int q0base = blockIdx.x * 128;

    __shared__ unsigned int Y_s[PP][64];
    __shared__ float rw1_s[PP][16];
    __shared__ float rw2_s[15][16], rw3_s[15][16];
    __shared__ float rw4_s[16], rb1_s[16], rb2_s[16], rb3_s[16];
    __shared__ float wred[4];

    // stage Y tile (u32 = 2 bf16), coalesced
    const unsigned int* Yw = (const unsigned int*)(Yg + (size_t)bl * PP * QQ);
    for (int i = tid; i < PP * 64; i += 256) {
        int p = i >> 6, w = i & 63;
        int q = q0base + w * 2;
        Y_s[p][w] = (q < QQ) ? Yw[((size_t)p * QQ + q) >> 1] : 0u;
    }
    for (int i = tid; i < PP * 16; i += 256) { int r = i >> 4, c = i & 15; rw1_s[r][c] = (c < 15) ? rW1[r * 15 + c] : 0.f; }
    for (int i = tid; i < 240; i += 256) { int r = i >> 4, c = i & 15;
        rw2_s[r][c] = (c < 15) ? rW2[r * 15 + c] : 0.f;
        rw3_s[r][c] = (c < 15) ? rW3[r * 15 + c] : 0.f; }
    if (tid < 16) rw4_s[tid] = (tid < 15) ? rW4[tid] : 0.f;
    else if (tid < 32) { int j = tid - 16; rb1_s[j] = (j < 15) ? rb1[j] : 0.f; }
    else if (tid < 48) { int j = tid - 32; rb2_s[j] = (j < 15) ? rb2[j] : 0.f; }
    else if (tid < 64) { int j = tid - 48; rb3_s[j] = (j < 15) ? rb3[j] : 0.f; }
    float rb4v = rb4[0];
    __syncthreads();

    int t = tid & 3, qs = tid >> 2;                // qs 0..63
    int q0 = q0base + qs * 2;
    bool act = (q0 < QQ);
    int qc = act ? q0 : 0;
    int2 gtv = *(const int2*)(G_true + b * QQ + qc);
    int gt0 = gtv.x, gt1 = gtv.y;

    float a0[15], a1[15];
    #pragma unroll
    for (int j = 0; j < 15; j++) { a0[j] = rb1_s[j]; a1[j] = rb1_s[j]; }

    const unsigned long long* Mp0 = Mpk + (size_t)b * 4 * QQ + qc;

    #pragma unroll 1
    for (int c = 0; c < 4; c++) {
        ulonglong2 mv = *(const ulonglong2*)(Mp0 + (size_t)c * QQ);
        unsigned long long mm0 = mv.x, mm1 = mv.y;
        #pragma unroll 1
        for (int i = 0; i < 25; i++) {
            int p = c * 25 + i;
            unsigned int yw = Y_s[p][qs];
            float y0 = bf2f((unsigned short)(yw & 0xffffu));
            float y1 = bf2f((unsigned short)(yw >> 16));
            int m0 = (int)(mm0 & 3ULL); mm0 >>= 2;
            int m1 = (int)(mm1 & 3ULL); mm1 >>= 2;
            float u0 = (m0 == t) ? y0 : (1.0f - y0) * (1.0f / 3.0f);
            float u1 = (m1 == t) ? y1 : (1.0f - y1) * (1.0f / 3.0f);
            float wrow[16];
            const float4* wr = (const float4*)rw1_s[p];
            ((float4*)wrow)[0] = wr[0]; ((float4*)wrow)[1] = wr[1];
            ((float4*)wrow)[2] = wr[2]; ((float4*)wrow)[3] = wr[3];
            #pragma unroll
            for (int j = 0; j < 15; j++) {
                a0[j] = fmaf(u0, wrow[j], a0[j]);
                a1[j] = fmaf(u1, wrow[j], a1[j]);
            }
        }
    }

    // tail for both q's, sharing weight-row fetches
    float g1a[15], g1b[15], g2a[15], g2b[15];
    #pragma unroll
    for (int j = 0; j < 15; j++) {
        g1a[j] = ftanh(a0[j]); g1b[j] = ftanh(a1[j]);
        g2a[j] = rb2_s[j];     g2b[j] = rb2_s[j];
    }
    #pragma unroll
    for (int j1 = 0; j1 < 15; j1++) {
        float wrow[16];
        const float4* wr = (const float4*)rw2_s[j1];
        ((float4*)wrow)[0] = wr[0]; ((float4*)wrow)[1] = wr[1];
        ((float4*)wrow)[2] = wr[2]; ((float4*)wrow)[3] = wr[3];
        float xa = g1a[j1], xb = g1b[j1];
        #pragma unroll
        for (int j2 = 0; j2 < 15; j2++) {
            g2a[j2] = fmaf(xa, wrow[j2], g2a[j2]);
            g2b[j2] = fmaf(xb, wrow[j2], g2b[j2]);
        }
    }
    #pragma unroll
    for (int j = 0; j < 15; j++) {
        g2a[j] = ftanh(g2a[j]); g2b[j] = ftanh(g2b[j]);
        a0[j] = rb3_s[j];       a1[j] = rb3_s[j];
    }
    #pragma unroll
    for (int j1 = 0; j1 < 15; j1++) {
        float wrow[16];
        const float4* wr = (const float4*)rw3_s[j1];
        ((float4*)wrow)[0] = wr[0]; ((float4*)wrow)[1] = wr[1];
        ((float4*)wrow)[2] = wr[2]; ((float4*)wrow)[3] = wr[3];
        float xa = g2a[j1], xb = g2b[j1];
        #pragma unroll
        for (int j2 = 0; j2 < 15; j2++) {
            a0[j2] = fmaf(xa, wrow[j2], a0[j2]);
            a1[j2] = fmaf(xb, wrow[j2], a1[j2]);
        }
    }
    float z0 = rb4v, z1 = rb4v;
    #pragma unroll
    for (int j = 0; j < 15; j++) {
        z0 = fmaf(ftanh(a0[j]), rw4_s[j], z0);
        z1 = fmaf(ftanh(a1[j]), rw4_s[j], z1);
    }

    float lrv = 0.f;
    {
        float zm = fmaxf(z0, __shfl_xor(z0, 1)); zm = fmaxf(zm, __shfl_xor(zm, 2));
        float ez = __expf(z0 - zm);
        float es = ez + __shfl_xor(ez, 1); es += __shfl_xor(es, 2);
        float prob = ez * frcp(es);
        float pm = fmaxf(prob, __shfl_xor(prob, 1)); pm = fmaxf(pm, __shfl_xor(pm, 2));
        float ep = __expf(prob - pm);
        float eps_ = ep + __shfl_xor(ep, 1); eps_ += __shfl_xor(eps_, 2);
        float lp = prob - (pm + __logf(eps_));
        float sel = (t == gt0) ? lp : 0.f;
        sel += __shfl_xor(sel, 1); sel += __shfl_xor(sel, 2);
        if (t == 0 && act) lrv += sel;
    }
    {
        float zm = fmaxf(z1, __shfl_xor(z1, 1)); zm = fmaxf(zm, __shfl_xor(zm, 2));
        float ez = __expf(z1 - zm);
        float es = ez + __shfl_xor(ez, 1); es += __shfl_xor(es, 2);
        float prob = ez * frcp(es);
        float pm = fmaxf(prob, __shfl_xor(prob, 1)); pm = fmaxf(pm, __shfl_xor(pm, 2));
        float ep = __expf(prob - pm);
        float eps_ = ep + __shfl_xor(ep, 1); eps_ += __shfl_xor(eps_, 2);
        float lp = prob - (pm + __logf(eps_));
        float sel = (t == gt1) ? lp : 0.f;
        sel += __shfl_xor(sel, 1); sel += __shfl_xor(sel, 2);
        if (t == 0 && act) lrv += sel;
    }

    float v = lrv;
    #pragma unroll
    for (int off = 32; off > 0; off >>= 1) v += __shfl_down(v, off);
    if ((tid & 63) == 0) wred[tid >> 6] = v;
    __syncthreads();
    if (tid == 0) atomicAdd(&acc[1], (double)(wred[0] + wred[1] + wred[2] + wred[3]));
}

// ---------------- K7: finalize ----------------
__global__ void k7_final(const double* __restrict__ acc, float* __restrict__ out) {
    if (threadIdx.x == 0) {
        out[0] = (float)(-acc[0] / (double)(BB * PP * QQ));
        out[1] = (float)(-acc[1] / (double)(BB * QQ));
    }
}

extern "C" void kernel_launch(void* const* d_in, const int* in_sizes, int n_in,
                              void* d_out, int out_size, void* d_ws, size_t ws_size,
                              hipStream_t stream) {
    const int*   M      = (const int*)d_in[0];
    const int*   G_true = (const int*)d_in[1];
    const float* cW1 = (const float*)d_in[2];  const float* cb1 = (const float*)d_in[3];
    const float* cW2 = (const float*)d_in[4];  const float* cb2 = (const float*)d_in[5];
    const float* cW3 = (const float*)d_in[6];  const float* cb3 = (const float*)d_in[7];
    const float* cW4 = (const float*)d_in[8];  const float* cb4 = (const float*)d_in[9];
    const float* rW1 = (const float*)d_in[10]; const float* rb1 = (const float*)d_in[11];
    const float* rW2 = (const float*)d_in[12]; const float* rb2 = (const float*)d_in[13];
    const float* rW3 = (const float*)d_in[14]; const float* rb3 = (const float*)d_in[15];
    const float* rW4 = (const float*)d_in[16]; const float* rb4 = (const float*)d_in[17];

    char* ws = (char*)d_ws;
    double* acc             = (double*)ws;                        // 16 B
    float* pa               = (float*)(ws + 64);                  // 38400
    int* count_a            = (int*)(ws + 38464);                 // 3200
    unsigned char* ghat     = (unsigned char*)(ws + 41664);       // 80000
    unsigned char* cd       = (unsigned char*)(ws + 121664);      // 80000
    unsigned char* bind     = (unsigned char*)(ws + 201664);      // 80000
    unsigned long long* bmk = (unsigned long long*)(ws + 281664); // 1280
    unsigned long long* Mpk = (unsigned long long*)(ws + 282944); // 2,560,000
    unsigned short* Y       = (unsigned short*)(ws + 2842944);    // nb * 2,000,000

    const size_t FIXED_END = 2842944;
    const size_t PER_B_Y = (size_t)PP * QQ * 2;
    size_t avail = (ws_size > FIXED_END) ? ws_size - FIXED_END : 0;
    int nb = (int)(avail / PER_B_Y);
    if (nb < 1) nb = 1;
    if (nb > BB) nb = BB;

    hipMemsetAsync(d_ws, 0, 16, stream);           // zero loss accumulators

    dim3 gq(157, BB);
    k1_ghat<<<gq, 256, 0, stream>>>(M, Mpk, ghat, cd);
    k4_bind<<<BB, 256, 0, stream>>>(cd, bind);
    k2_counts<<<BB * PP, 256, 0, stream>>>(Mpk, ghat, bind, count_a, pa, cW1);
    k3_bina<<<BB, 128, 0, stream>>>(count_a, bmk);

    for (int b0 = 0; b0 < BB; b0 += nb) {
        int g = (BB - b0 < nb) ? (BB - b0) : nb;
        dim3 ga(157, g);
        dim3 gb(79, g);
        k6a_y<<<ga, 256, 0, stream>>>(Mpk, G_true, ghat, cd, pa, bmk,
            cW1, cb1, cW2, cb2, cW3, cb3, cW4, cb4, Y, b0, acc);
        k6b_ref<<<gb, 256, 0, stream>>>(Mpk, G_true, Y, rW1,
            rb1, rW2, rb2, rW3, rb3, rW4, rb4, b0, acc);
    }
    k7_final<<<1, 1, 0, stream>>>(acc, (float*)d_out);
}